// Round 24
// baseline (213.301 us; speedup 1.0000x reference)
//
#include <hip/hip_runtime.h>
#include <hip/hip_bf16.h>
#include <math.h>

// ---------------------------------------------------------------------------
// PMLP_GCN forward:  3x (GEMM -> GCN-agg[+bias]) with BN+ReLU between,
// log_softmax at the end.  N=50000 E=640000 IN=500 HID=128 OUT=64, f32.
// R20: mgemm0 A-operand held ENTIRELY in registers (16 MFMA fragments =
//      64 VGPR/lane, loaded once from global with fully-unrolled static
//      indexing): no A LDS round-trip, no A barriers, x read exactly once.
//      W keeps the gload_lds double-buffer (32 KB). Kp=512 unrolled.
// ---------------------------------------------------------------------------

#define EPS_BN 1e-5f

typedef __attribute__((ext_vector_type(8))) _Float16 f16x8;
typedef __attribute__((ext_vector_type(4))) _Float16 f16x4;
typedef __attribute__((ext_vector_type(2))) _Float16 f16x2;
typedef __attribute__((ext_vector_type(4))) float    f32x4;

__device__ __forceinline__ void gload16(const void* g, void* l) {
    __builtin_amdgcn_global_load_lds(
        (const __attribute__((address_space(1))) void*)g,
        (__attribute__((address_space(3))) void*)l, 16, 0, 0);
}

// ---------------- graph prep ----------------

// blocks [0,gE): edge counting.  blocks [gE, gE+88): W0/W1/W2 f32->f16.
__global__ void countw_k(const int* __restrict__ src, const int* __restrict__ dst,
                         int* __restrict__ cnt, int E, int gE,
                         const float* __restrict__ W0, _Float16* __restrict__ W0h,
                         const float* __restrict__ W1, _Float16* __restrict__ W1h,
                         const float* __restrict__ W2, _Float16* __restrict__ W2h) {
    if (blockIdx.x < (unsigned)gE) {
        int e = blockIdx.x * 256 + threadIdx.x;
        if (e >= E) return;
        int s = src[e], d = dst[e];
        if (s != d) atomicAdd(&cnt[d], 1);
        return;
    }
    int idx = (blockIdx.x - gE) * 256 + threadIdx.x;   // 0..22527
    if (idx < 16384) {
        int r = idx >> 7, k4 = (idx & 127) * 4;
        f16x4 h = {(_Float16)0.f, (_Float16)0.f, (_Float16)0.f, (_Float16)0.f};
        if (k4 < 500) {
            float4 v = *(const float4*)(W0 + (size_t)r * 500 + k4);
            h[0] = (_Float16)v.x; h[1] = (_Float16)v.y;
            h[2] = (_Float16)v.z; h[3] = (_Float16)v.w;
        }
        *(f16x4*)(W0h + (size_t)r * 512 + k4) = h;
    } else if (idx < 16384 + 4096) {
        int t = idx - 16384;
        float4 v = *(const float4*)(W1 + (size_t)t * 4);
        f16x4 h;
        h[0] = (_Float16)v.x; h[1] = (_Float16)v.y;
        h[2] = (_Float16)v.z; h[3] = (_Float16)v.w;
        *(f16x4*)(W1h + (size_t)t * 4) = h;
    } else if (idx < 22528) {
        int t = idx - 20480;
        float4 v = *(const float4*)(W2 + (size_t)t * 4);
        f16x4 h;
        h[0] = (_Float16)v.x; h[1] = (_Float16)v.y;
        h[2] = (_Float16)v.z; h[3] = (_Float16)v.w;
        *(f16x4*)(W2h + (size_t)t * 4) = h;
    }
}

// block-level exclusive prefix scan over cnt[n] (512-windows)
__global__ void scan1_k(const int* __restrict__ cnt, int* __restrict__ within,
                        int* __restrict__ btot, int n) {
    __shared__ int s[512];
    int tid = threadIdx.x;
    int i = blockIdx.x * 512 + tid;
    int val = (i < n) ? cnt[i] : 0;
    s[tid] = val;
    __syncthreads();
    for (int off = 1; off < 512; off <<= 1) {
        int v = (tid >= off) ? s[tid - off] : 0;
        __syncthreads();
        s[tid] += v;
        __syncthreads();
    }
    if (i < n) within[i] = s[tid] - val;   // exclusive
    if (tid == 511) btot[blockIdx.x] = s[511];
}

// merged: window-offset reduce + row_start/cursor + degree transforms
__global__ void scan3_k(const int* __restrict__ within, const int* __restrict__ btot,
                        const int* __restrict__ cnt, int* __restrict__ row_start,
                        int* __restrict__ cursor, float* __restrict__ dinv,
                        float* __restrict__ invdeg, int n) {
    __shared__ int sred[256];
    const int tid = threadIdx.x;
    const int w = (blockIdx.x * 256) >> 9;          // 512-window index (<= 97)
    sred[tid] = (tid < w) ? btot[tid] : 0;
    __syncthreads();
    #pragma unroll
    for (int off = 128; off >= 1; off >>= 1) {
        if (tid < off) sred[tid] += sred[tid + off];
        __syncthreads();
    }
    const int base = sred[0];
    int i = blockIdx.x * 256 + tid;
    if (i < n) {
        int rs = within[i] + base;
        row_start[i] = rs;
        cursor[i]    = rs;
        float deg = (float)cnt[i] + 1.0f;           // +1 for added self loop
        dinv[i]   = rsqrtf(deg);
        invdeg[i] = 1.0f / deg;
    }
}

// ---------------- MFMA GEMM: C[M,NC] = BN?(A)[M,K] * Wh[NC,Kp]^T ------------
// Wh f16 (padded Kp, pad=0). f32 accumulate, f16 out. 4 waves; tile 64 x NC.
// !AF32: A f16 via global_load_lds, A+W double-buffered (48 KB, 3 blocks/CU).
// AF32 (layer 0, K=500/Kp=512 HARDCODED): each lane loads its 16 MFMA A
//   fragments (row = wave*16+lrow; elems c*64+ks*32+kg*8..+8) straight from
//   global x as 2 float4s each (fully unrolled -> static indices), converts
//   to f16 and keeps them in 64 VGPRs. No A LDS, no A barriers; x read once.
//   OOB rows clamp to row 0 (outputs unguarded rows never stored); pad cols
//   clamp to col 0 (finite garbage x 0-padded W = 0). W double-buffered via
//   gload_lds (32 KB).
// FILL=true: blocks >= gM run the CSR fill (independent, overlapped).
// BN=true (Kp==128): per-k scale/shift from LDS applied to the A fragment.

template <int NC, bool BN, bool AF32, bool FILL>
__global__ __launch_bounds__(256) void mgemm_k(const void* __restrict__ Av,
                                               const _Float16* __restrict__ Wh,
                                               _Float16* __restrict__ C,
                                               const float* __restrict__ gsum,
                                               const float* __restrict__ gsq,
                                               float inv_n, int M, int K, int Kp,
                                               const int* __restrict__ src,
                                               const int* __restrict__ dst,
                                               const float* __restrict__ dinv,
                                               int* __restrict__ cursor,
                                               int2* __restrict__ epk,
                                               int E, int gM) {
    constexpr int CT = NC / 16;            // col frags per wave
    constexpr int WJ = NC / 32;            // W gload insts per wave
    constexpr int ASZ = AF32 ? 16 : (2 * 64 * 64);   // A LDS only if !AF32
    __shared__ __align__(16) _Float16 As[ASZ];
    __shared__ __align__(16) _Float16 Ws[2][NC * 64];
    __shared__ __align__(16) float ssc[128], ssh[128];  // dead-stripped if !BN

    if constexpr (FILL) {
        if ((int)blockIdx.x >= gM) {       // fill path: no barriers used
            int e = (blockIdx.x - gM) * 256 + threadIdx.x;
            if (e < E) {
                int s = src[e], d = dst[e];
                if (s != d) {
                    int pos = atomicAdd(&cursor[d], 1);
                    epk[pos] = make_int2(s, __float_as_int(dinv[s] * dinv[d]));
                }
            }
            return;
        }
    }

    const int tid  = threadIdx.x;
    const int lane = tid & 63, wave = tid >> 6;
    const int lrow = lane & 15, kg = lane >> 4;
    const int row0 = blockIdx.x * 64;

    f32x4 acc[CT] = {};

    const float*    Af = (const float*)Av;
    const _Float16* Ah = (const _Float16*)Av;

    auto stage = [&](int c0, int b) {
        const int k0 = c0 * 64;
        if constexpr (!AF32) {
            #pragma unroll
            for (int j = 0; j < 2; ++j) {
                int li  = wave * 128 + j * 64 + lane;      // 0..511
                int row = li >> 3, s = li & 7;
                int gr  = row0 + row;
                int gs  = s ^ (row & 7);
                if (gr < M)
                    gload16(Ah + (size_t)gr * Kp + k0 + gs * 8,
                            (char*)As + b * (64 * 64 * 2) +
                            (wave * 128 + j * 64) * 16);
            }
        }
        #pragma unroll
        for (int j = 0; j < WJ; ++j) {
            int li  = wave * (WJ * 64) + j * 64 + lane;
            int row = li >> 3, s = li & 7;
            int gs  = s ^ (row & 7);
            gload16(Wh + (size_t)row * Kp + k0 + gs * 8,
                    (char*)&Ws[b][0] + (wave * WJ + j) * 1024);
        }
    };

    // shared W-fragment read + MFMA tail (af already in registers)
    auto mfma_with = [&](f16x8 af, int b) {
        const char* WsB = (const char*)&Ws[b][0];
        return af; (void)WsB;  // placeholder (not used; see compute paths)
    };

    if constexpr (BN) {
        if (tid < 128) {                   // Kp == 128 on the BN path
            float mean = gsum[tid] * inv_n;
            float var  = gsq[tid] * inv_n - mean * mean;
            float sc   = rsqrtf(var + EPS_BN);
            ssc[tid] = sc;
            ssh[tid] = -mean * sc;
        }
    }

    if constexpr (AF32) {
        // ---- A fragments -> registers (K=500, Kp=512, 8 chunks) ----
        const int row = wave * 16 + lrow;
        const int gr  = row0 + row;
        const float* rowp = Af + (size_t)(gr < M ? gr : 0) * (size_t)500;
        f16x8 afr[16];                     // [c*2+ks], static indices only
        #pragma unroll
        for (int f = 0; f < 16; ++f) {
            const int c  = f >> 1, ks = f & 1;
            const int e0 = c * 64 + ks * 32 + kg * 8;       // element base
            const int e1 = e0 + 4;
            float4 v0 = *(const float4*)(rowp + ((e0 + 4 <= 500) ? e0 : 0));
            float4 v1 = *(const float4*)(rowp + ((e1 + 4 <= 500) ? e1 : 0));
            f16x8 h;
            h[0] = (_Float16)v0.x; h[1] = (_Float16)v0.y;
            h[2] = (_Float16)v0.z; h[3] = (_Float16)v0.w;
            h[4] = (_Float16)v1.x; h[5] = (_Float16)v1.y;
            h[6] = (_Float16)v1.z; h[7] = (_Float16)v1.w;
            afr[f] = h;
        }
        stage(0, 0);                       // W(0)
        asm volatile("s_waitcnt vmcnt(0) lgkmcnt(0)" ::: "memory");
        __builtin_amdgcn_s_barrier();
        __builtin_amdgcn_sched_barrier(0);

        #pragma unroll
        for (int c = 0; c < 8; ++c) {
            const int b = c & 1;
            if (c + 1 < 8) stage(c + 1, b ^ 1);
            const char* WsB = (const char*)&Ws[b][0];
            #pragma unroll
            for (int ks = 0; ks < 2; ++ks) {
                const int cb = ks * 64 + kg * 16;
                f16x8 bf[CT];
                #pragma unroll
                for (int ct = 0; ct < CT; ++ct) {
                    int r2 = ct * 16 + lrow;
                    bf[ct] = *(const f16x8*)(WsB + r2 * 128 +
                                             (cb ^ ((r2 & 7) << 4)));
                }
                #pragma unroll
                for (int ct = 0; ct < CT; ++ct)
                    acc[ct] = __builtin_amdgcn_mfma_f32_16x16x32_f16(
                        afr[c * 2 + ks], bf[ct], acc[ct], 0, 0, 0);
            }
            if (c + 1 < 8) {
                asm volatile("s_waitcnt vmcnt(0) lgkmcnt(0)" ::: "memory");
                __builtin_amdgcn_s_barrier();
                __builtin_amdgcn_sched_barrier(0);
            }
        }
    } else {
        const int nchunk = Kp >> 6;        // Kp % 64 == 0
        stage(0, 0);
        asm volatile("s_waitcnt vmcnt(0) lgkmcnt(0)" ::: "memory");
        __builtin_amdgcn_s_barrier();
        __builtin_amdgcn_sched_barrier(0);
        for (int c = 0; c < nchunk; ++c) {
            const int b = c & 1;
            const bool more = (c + 1 < nchunk);
            if (more) stage(c + 1, b ^ 1);
            {
                const char* AsB = (const char*)As + b * (64 * 64 * 2);
                const char* WsB = (const char*)&Ws[b][0];
                const int kofs = c * 64;
                #pragma unroll
                for (int ks = 0; ks < 2; ++ks) {
                    const int cb = ks * 64 + kg * 16;
                    f16x8 af, bf[CT];
                    {
                        int row = wave * 16 + lrow;
                        af = *(const f16x8*)(AsB + row * 128 +
                                             (cb ^ ((row & 7) << 4)));
                    }
                    if constexpr (BN) {
                        const int kb = kofs + ks * 32 + kg * 8;
                        f32x4 sc0 = *(const f32x4*)&ssc[kb];
                        f32x4 sc1 = *(const f32x4*)&ssc[kb + 4];
                        f32x4 sh0 = *(const f32x4*)&ssh[kb];
                        f32x4 sh1 = *(const f32x4*)&ssh[kb + 4];
                        f16x8 a2;
                        #pragma unroll
                        for (int j = 0; j < 4; ++j) {
                            a2[j]     = (_Float16)fmaxf(0.f, fmaf((float)af[j],     sc0[j], sh0[j]));
                            a2[j + 4] = (_Float16)fmaxf(0.f, fmaf((float)af[j + 4], sc1[j], sh1[j]));
                        }
                        af = a2;
                    }
                    #pragma unroll
                    for (int ct = 0; ct < CT; ++ct) {
                        int row = ct * 16 + lrow;
                        bf[ct] = *(const f16x8*)(WsB + row * 128 +
                                                 (cb ^ ((row & 7) << 4)));
                    }
                    #pragma unroll
                    for (int ct = 0; ct < CT; ++ct)
                        acc[ct] = __builtin_amdgcn_mfma_f32_16x16x32_f16(
                            af, bf[ct], acc[ct], 0, 0, 0);
                }
            }
            if (more) {
                asm volatile("s_waitcnt vmcnt(0) lgkmcnt(0)" ::: "memory");
                __builtin_amdgcn_s_barrier();
                __builtin_amdgcn_sched_barrier(0);
            }
        }
    }

    // ---- epilogue: D lane map col=lane&15, row=(lane>>4)*4+r ----
    #pragma unroll
    for (int r = 0; r < 4; ++r) {
        int grow = row0 + wave * 16 + kg * 4 + r;
        if (grow >= M) continue;
        #pragma unroll
        for (int ct = 0; ct < CT; ++ct)
            C[(size_t)grow * NC + ct * 16 + lrow] = (_Float16)acc[ct][r];
    }
}

// ---------------- GCN aggregation (gather over CSR, f16 in/out) ----------------
// 4 nodes/wave (16 lanes x f16x8), software-pipelined edge records (R14).

__global__ void agg128_k(const _Float16* __restrict__ h, const float* __restrict__ invdeg,
                         const int* __restrict__ row_start, const int* __restrict__ cnt,
                         const int2* __restrict__ epk,
                         const float* __restrict__ bias, _Float16* __restrict__ out, int n) {
    const int grp = threadIdx.x >> 4;           // 0..15 node-groups per block
    const int l = threadIdx.x & 15;
    const int i = blockIdx.x * 16 + grp;
    if (i >= n) return;
    const int st = row_start[i], en = st + cnt[i];
    const float id = invdeg[i];
    const int c = l * 8;

    float a[8];
    {
        f16x8 hv = *(const f16x8*)(h + (size_t)i * 128 + c);
        #pragma unroll
        for (int j = 0; j < 8; ++j)
            a[j] = fmaf(id, (float)hv[j], bias[c + j]);
    }

    auto gfma = [&](int2 e0, int2 e1, int2 e2, int2 e3) {
        f16x8 v0 = *(const f16x8*)(h + (size_t)e0.x * 128 + c);
        f16x8 v1 = *(const f16x8*)(h + (size_t)e1.x * 128 + c);
        f16x8 v2 = *(const f16x8*)(h + (size_t)e2.x * 128 + c);
        f16x8 v3 = *(const f16x8*)(h + (size_t)e3.x * 128 + c);
        float w0 = __int_as_float(e0.y), w1 = __int_as_float(e1.y);
        float w2 = __int_as_float(e2.y), w3 = __int_as_float(e3.y);
        #pragma unroll
        for (int j = 0; j < 8; ++j) {
            a[j] = fmaf(w0, (float)v0[j], a[j]);
            a[j] = fmaf(w1, (float)v1[j], a[j]);
            a[j] = fmaf(w2, (float)v2[j], a[j]);
            a[j] = fmaf(w3, (float)v3[j], a[j]);
        }
    };

    int p = st;
    if (p + 3 < en) {
        int2 eA0 = epk[p], eA1 = epk[p + 1], eA2 = epk[p + 2], eA3 = epk[p + 3];
        while (p + 7 < en) {
            int2 eB0 = epk[p + 4], eB1 = epk[p + 5];
            int2 eB2 = epk[p + 6], eB3 = epk[p + 7];
            gfma(eA0, eA1, eA2, eA3);
            eA0 = eB0; eA1 = eB1; eA2 = eB2; eA3 = eB3;
            p += 4;
        }
        gfma(eA0, eA1, eA2, eA3);
        p += 4;
    }
    for (; p < en; ++p) {
        int2 e0 = epk[p];
        float w0 = __int_as_float(e0.y);
        f16x8 v0 = *(const f16x8*)(h + (size_t)e0.x * 128 + c);
        #pragma unroll
        for (int j = 0; j < 8; ++j)
            a[j] = fmaf(w0, (float)v0[j], a[j]);
    }
    f16x8 o;
    #pragma unroll
    for (int j = 0; j < 8; ++j) o[j] = (_Float16)a[j];
    *(f16x8*)(out + (size_t)i * 128 + c) = o;
}

// ---------------- BN stats over f16 activations (12.8 MB read) ----------------

__global__ void stats16_k(const _Float16* __restrict__ a, float* __restrict__ gsum,
                          float* __restrict__ gsq, int total8) {
    const int tid = threadIdx.x;
    float s[8] = {}, q[8] = {};
    for (int idx = blockIdx.x * 256 + tid; idx < total8; idx += gridDim.x * 256) {
        f16x8 v = *(const f16x8*)(a + (size_t)idx * 8);
        #pragma unroll
        for (int j = 0; j < 8; ++j) {
            float f = (float)v[j];
            s[j] += f;
            q[j] = fmaf(f, f, q[j]);
        }
    }
    __shared__ float red[2][16][16][8];     // [sum/sq][k-group][col-group][col]
    const int g = tid & 15, k = tid >> 4;
    #pragma unroll
    for (int j = 0; j < 8; ++j) {
        red[0][k][g][j] = s[j];
        red[1][k][g][j] = q[j];
    }
    __syncthreads();
    if (tid < 128) {
        const int g2 = tid & 15, j2 = tid >> 4;     // j2 in 0..7
        float ts = 0.f, tq = 0.f;
        #pragma unroll
        for (int k2 = 0; k2 < 16; ++k2) {
            ts += red[0][k2][g2][j2];
            tq += red[1][k2][g2][j2];
        }
        atomicAdd(&gsum[g2 * 8 + j2], ts);
        atomicAdd(&gsq[g2 * 8 + j2], tq);
    }
}

// ---- classifier agg (64 cols) + log_softmax; 8 nodes/wave, pipelined ----
// 8 lanes per node, f16x8 per lane (full row); shfl_xor d<=4 stays in-group.

__global__ void aggsm_k(const _Float16* __restrict__ h, const float* __restrict__ invdeg,
                        const int* __restrict__ row_start, const int* __restrict__ cnt,
                        const int2* __restrict__ epk,
                        const float* __restrict__ bias, float* __restrict__ out, int n) {
    const int grp = threadIdx.x >> 3;           // 0..31 node-groups per block
    const int l = threadIdx.x & 7;
    const int i = blockIdx.x * 32 + grp;
    if (i >= n) return;
    const int st = row_start[i], en = st + cnt[i];
    const float id = invdeg[i];
    const int c = l * 8;

    float a[8];
    {
        f16x8 hv = *(const f16x8*)(h + (size_t)i * 64 + c);
        #pragma unroll
        for (int j = 0; j < 8; ++j)
            a[j] = fmaf(id, (float)hv[j], bias[c + j]);
    }

    auto gfma = [&](int2 e0, int2 e1, int2 e2, int2 e3) {
        f16x8 v0 = *(const f16x8*)(h + (size_t)e0.x * 64 + c);
        f16x8 v1 = *(const f16x8*)(h + (size_t)e1.x * 64 + c);
        f16x8 v2 = *(const f16x8*)(h + (size_t)e2.x * 64 + c);
        f16x8 v3 = *(const f16x8*)(h + (size_t)e3.x * 64 + c);
        float w0 = __int_as_float(e0.y), w1 = __int_as_float(e1.y);
        float w2 = __int_as_float(e2.y), w3 = __int_as_float(e3.y);
        #pragma unroll
        for (int j = 0; j < 8; ++j) {
            a[j] = fmaf(w0, (float)v0[j], a[j]);
            a[j] = fmaf(w1, (float)v1[j], a[j]);
            a[j] = fmaf(w2, (float)v2[j], a[j]);
            a[j] = fmaf(w3, (float)v3[j], a[j]);
        }
    };

    int p = st;
    if (p + 3 < en) {
        int2 eA0 = epk[p], eA1 = epk[p + 1], eA2 = epk[p + 2], eA3 = epk[p + 3];
        while (p + 7 < en) {
            int2 eB0 = epk[p + 4], eB1 = epk[p + 5];
            int2 eB2 = epk[p + 6], eB3 = epk[p + 7];
            gfma(eA0, eA1, eA2, eA3);
            eA0 = eB0; eA1 = eB1; eA2 = eB2; eA3 = eB3;
            p += 4;
        }
        gfma(eA0, eA1, eA2, eA3);
        p += 4;
    }
    for (; p < en; ++p) {
        int2 e0 = epk[p];
        float w0 = __int_as_float(e0.y);
        f16x8 v0 = *(const f16x8*)(h + (size_t)e0.x * 64 + c);
        #pragma unroll
        for (int j = 0; j < 8; ++j)
            a[j] = fmaf(w0, (float)v0[j], a[j]);
    }

    // fused log_softmax over 64 cols held by this 8-lane group
    float m = a[0];
    #pragma unroll
    for (int j = 1; j < 8; ++j) m = fmaxf(m, a[j]);
    #pragma unroll
    for (int d = 4; d >= 1; d >>= 1) m = fmaxf(m, __shfl_xor(m, d, 64));
    float s = 0.f;
    float e[8];
    #pragma unroll
    for (int j = 0; j < 8; ++j) { e[j] = __expf(a[j] - m); s += e[j]; }
    #pragma unroll
    for (int d = 4; d >= 1; d >>= 1) s += __shfl_xor(s, d, 64);
    float ls = __logf(s);
    float4 o0 = make_float4(a[0] - m - ls, a[1] - m - ls,
                            a[2] - m - ls, a[3] - m - ls);
    float4 o1 = make_float4(a[4] - m - ls, a[5] - m - ls,
                            a[6] - m - ls, a[7] - m - ls);
    *(float4*)(out + (size_t)i * 64 + c)     = o0;
    *(float4*)(out + (size_t)i * 64 + c + 4) = o1;
}

// ---------------------------------------------------------------------------

extern "C" void kernel_launch(void* const* d_in, const int* in_sizes, int n_in,
                              void* d_out, int out_size, void* d_ws, size_t ws_size,
                              hipStream_t stream) {
    const float* x  = (const float*)d_in[0];
    const int*   ei = (const int*)d_in[1];
    const float* W0 = (const float*)d_in[2];
    const float* b0 = (const float*)d_in[3];
    const float* W1 = (const float*)d_in[4];
    const float* b1 = (const float*)d_in[5];
    const float* W2 = (const float*)d_in[6];
    const float* b2 = (const float*)d_in[7];

    const int IN = 500;
    const int n = in_sizes[0] / IN;      // 50000
    const int E = in_sizes[1] / 2;       // 640000
    const int* src = ei;
    const int* dst = ei + E;

    // ---- workspace bump allocator (256B aligned) ----
    char* p = (char*)d_ws;
    auto alloc = [&](size_t bytes) -> void* {
        char* r = p;
        p += (bytes + 255) & ~(size_t)255;
        return (void*)r;
    };
    _Float16*  hb1h    = (_Float16*)alloc((size_t)n * 128 * 2);  // GEMM out / agg in
    _Float16*  hb2a    = (_Float16*)alloc((size_t)n * 128 * 2);  // agg out (pre-BN f16)
    _Float16*  W0h     = (_Float16*)alloc((size_t)128 * 512 * 2);
    _Float16*  W1h     = (_Float16*)alloc((size_t)128 * 128 * 2);
    _Float16*  W2h     = (_Float16*)alloc((size_t)64 * 128 * 2);
    // deg_cnt + BN stat buffers allocated contiguously -> single memset
    int*   deg_cnt  = (int*)alloc((size_t)n * 4);
    float* gsum0    = (float*)alloc(128 * 4);
    float* gsq0     = (float*)alloc(128 * 4);
    float* gsum1    = (float*)alloc(128 * 4);
    float* gsq1     = (float*)alloc(128 * 4);
    char*  zero_end = p;
    float* dinv     = (float*)alloc((size_t)n * 4);
    float* invdeg   = (float*)alloc((size_t)n * 4);
    int*   row_st   = (int*)alloc((size_t)n * 4);
    int*   cursor   = (int*)alloc((size_t)n * 4);
    int*   within   = (int*)alloc((size_t)n * 4);
    int*   btot     = (int*)alloc(256 * 4);
    int2*  epk      = (int2*)alloc((size_t)E * 8);
    (void)ws_size; (void)n_in; (void)out_size;

    float* out = (float*)d_out;
    const float inv_n = 1.0f / (float)n;

    const int gE = (E + 255) / 256;      // 2500
    const int gN = (n + 255) / 256;
    const int nblk = (n + 511) / 512;
    const int gM = (n + 63) / 64;        // 782 blocks
    const int gA = (n + 15) / 16;        // 3125 blocks (agg128)
    const int gS = (n + 31) / 32;        // 1563 blocks (aggsm, 8 nodes/wave)

    // ---- graph prep + weight conversion (once per call) ----
    hipMemsetAsync(deg_cnt, 0, (size_t)(zero_end - (char*)deg_cnt), stream);
    countw_k<<<gE + 88, 256, 0, stream>>>(src, dst, deg_cnt, E, gE,
                                          W0, W0h, W1, W1h, W2, W2h);
    scan1_k<<<nblk, 512, 0, stream>>>(deg_cnt, within, btot, n);
    scan3_k<<<gN, 256, 0, stream>>>(within, btot, deg_cnt, row_st, cursor,
                                    dinv, invdeg, n);

    // ---- layer 0: GEMM0 + CSR fill in ONE launch (independent work) ----
    mgemm_k<128, false, true, true><<<gM + gE, 256, 0, stream>>>(
        x, W0h, hb1h, nullptr, nullptr, 0.f, n, 500, 512,
        src, dst, dinv, cursor, epk, E, gM);
    agg128_k<<<gA, 256, 0, stream>>>(hb1h, invdeg, row_st, deg_cnt, epk, b0, hb2a, n);
    stats16_k<<<256, 256, 0, stream>>>(hb2a, gsum0, gsq0, n * 16);

    // ---- layer 1 (BN0+ReLU fused into GEMM1's A path) ----
    mgemm_k<128, true, false, false><<<gM, 256, 0, stream>>>(
        hb2a, W1h, hb1h, gsum0, gsq0, inv_n, n, 128, 128,
        nullptr, nullptr, nullptr, nullptr, nullptr, 0, gM);
    agg128_k<<<gA, 256, 0, stream>>>(hb1h, invdeg, row_st, deg_cnt, epk, b1, hb2a, n);
    stats16_k<<<256, 256, 0, stream>>>(hb2a, gsum1, gsq1, n * 16);

    // ---- classifier (BN1+ReLU fused into GEMM2; log_softmax fused into agg) ----
    mgemm_k<64, true, false, false><<<gM, 256, 0, stream>>>(
        hb2a, W2h, hb1h, gsum1, gsq1, inv_n, n, 128, 128,
        nullptr, nullptr, nullptr, nullptr, nullptr, 0, gM);
    aggsm_k<<<gS, 256, 0, stream>>>(hb1h, invdeg, row_st, deg_cnt, epk, b2, out, n);
}

// Round 25
// 206.627 us; speedup vs baseline: 1.0323x; 1.0323x over previous
//
#include <hip/hip_runtime.h>
#include <hip/hip_bf16.h>
#include <math.h>

// ---------------------------------------------------------------------------
// PMLP_GCN forward:  3x (GEMM -> GCN-agg[+bias]) with BN+ReLU between,
// log_softmax at the end.  N=50000 E=640000 IN=500 HID=128 OUT=64, f32.
// R21 == R19 (best measured, 206.7 us): mgemm0 LDS minimized to 32 KB
//      (A reg-staged f32->f16 dbuf 16KB + W SINGLE-buffered 16KB) -> 5
//      blocks/CU for the GEMM and the co-launched CSR-fill tail.
//      R16/R17/R18/R20 A-staging variants all measured neutral or worse;
//      this configuration is the empirical optimum of that family.
// ---------------------------------------------------------------------------

#define EPS_BN 1e-5f

typedef __attribute__((ext_vector_type(8))) _Float16 f16x8;
typedef __attribute__((ext_vector_type(4))) _Float16 f16x4;
typedef __attribute__((ext_vector_type(2))) _Float16 f16x2;
typedef __attribute__((ext_vector_type(4))) float    f32x4;

__device__ __forceinline__ void gload16(const void* g, void* l) {
    __builtin_amdgcn_global_load_lds(
        (const __attribute__((address_space(1))) void*)g,
        (__attribute__((address_space(3))) void*)l, 16, 0, 0);
}

// ---------------- graph prep ----------------

// blocks [0,gE): edge counting.  blocks [gE, gE+88): W0/W1/W2 f32->f16.
__global__ void countw_k(const int* __restrict__ src, const int* __restrict__ dst,
                         int* __restrict__ cnt, int E, int gE,
                         const float* __restrict__ W0, _Float16* __restrict__ W0h,
                         const float* __restrict__ W1, _Float16* __restrict__ W1h,
                         const float* __restrict__ W2, _Float16* __restrict__ W2h) {
    if (blockIdx.x < (unsigned)gE) {
        int e = blockIdx.x * 256 + threadIdx.x;
        if (e >= E) return;
        int s = src[e], d = dst[e];
        if (s != d) atomicAdd(&cnt[d], 1);
        return;
    }
    int idx = (blockIdx.x - gE) * 256 + threadIdx.x;   // 0..22527
    if (idx < 16384) {
        int r = idx >> 7, k4 = (idx & 127) * 4;
        f16x4 h = {(_Float16)0.f, (_Float16)0.f, (_Float16)0.f, (_Float16)0.f};
        if (k4 < 500) {
            float4 v = *(const float4*)(W0 + (size_t)r * 500 + k4);
            h[0] = (_Float16)v.x; h[1] = (_Float16)v.y;
            h[2] = (_Float16)v.z; h[3] = (_Float16)v.w;
        }
        *(f16x4*)(W0h + (size_t)r * 512 + k4) = h;
    } else if (idx < 16384 + 4096) {
        int t = idx - 16384;
        float4 v = *(const float4*)(W1 + (size_t)t * 4);
        f16x4 h;
        h[0] = (_Float16)v.x; h[1] = (_Float16)v.y;
        h[2] = (_Float16)v.z; h[3] = (_Float16)v.w;
        *(f16x4*)(W1h + (size_t)t * 4) = h;
    } else if (idx < 22528) {
        int t = idx - 20480;
        float4 v = *(const float4*)(W2 + (size_t)t * 4);
        f16x4 h;
        h[0] = (_Float16)v.x; h[1] = (_Float16)v.y;
        h[2] = (_Float16)v.z; h[3] = (_Float16)v.w;
        *(f16x4*)(W2h + (size_t)t * 4) = h;
    }
}

// block-level exclusive prefix scan over cnt[n] (512-windows)
__global__ void scan1_k(const int* __restrict__ cnt, int* __restrict__ within,
                        int* __restrict__ btot, int n) {
    __shared__ int s[512];
    int tid = threadIdx.x;
    int i = blockIdx.x * 512 + tid;
    int val = (i < n) ? cnt[i] : 0;
    s[tid] = val;
    __syncthreads();
    for (int off = 1; off < 512; off <<= 1) {
        int v = (tid >= off) ? s[tid - off] : 0;
        __syncthreads();
        s[tid] += v;
        __syncthreads();
    }
    if (i < n) within[i] = s[tid] - val;   // exclusive
    if (tid == 511) btot[blockIdx.x] = s[511];
}

// merged: window-offset reduce + row_start/cursor + degree transforms
__global__ void scan3_k(const int* __restrict__ within, const int* __restrict__ btot,
                        const int* __restrict__ cnt, int* __restrict__ row_start,
                        int* __restrict__ cursor, float* __restrict__ dinv,
                        float* __restrict__ invdeg, int n) {
    __shared__ int sred[256];
    const int tid = threadIdx.x;
    const int w = (blockIdx.x * 256) >> 9;          // 512-window index (<= 97)
    sred[tid] = (tid < w) ? btot[tid] : 0;
    __syncthreads();
    #pragma unroll
    for (int off = 128; off >= 1; off >>= 1) {
        if (tid < off) sred[tid] += sred[tid + off];
        __syncthreads();
    }
    const int base = sred[0];
    int i = blockIdx.x * 256 + tid;
    if (i < n) {
        int rs = within[i] + base;
        row_start[i] = rs;
        cursor[i]    = rs;
        float deg = (float)cnt[i] + 1.0f;           // +1 for added self loop
        dinv[i]   = rsqrtf(deg);
        invdeg[i] = 1.0f / deg;
    }
}

// ---------------- MFMA GEMM: C[M,NC] = BN?(A)[M,K] * Wh[NC,Kp]^T ------------
// Wh f16 (padded Kp). f32 accumulate, f16 out. 4 waves; tile 64 x NC; chunk 64.
// !AF32: A f16 via global_load_lds, A+W double-buffered (48 KB, 3 blocks/CU).
// AF32 (layer 0): A f32, reg-staged depth-1 (4 float4/thread, constant
//   indices -> SROA-safe), f32->f16 convert + swizzled ds_write into a
//   16 KB A double-buffer; W SINGLE-buffered (16 KB). Total LDS 32 KB ->
//   5 blocks/CU so the GEMM and the co-launched fill tail both get ~20
//   waves/CU. Per chunk: [load_a(c+1)] compute(c); store_a; barrier;
//   stageW(c+1); vmcnt(0); barrier.
// FILL=true: blocks >= gM run the CSR fill (independent, overlapped).
// BN=true (Kp==128): per-k scale/shift from LDS applied to the A fragment.

template <int NC, bool BN, bool AF32, bool FILL>
__global__ __launch_bounds__(256) void mgemm_k(const void* __restrict__ Av,
                                               const _Float16* __restrict__ Wh,
                                               _Float16* __restrict__ C,
                                               const float* __restrict__ gsum,
                                               const float* __restrict__ gsq,
                                               float inv_n, int M, int K, int Kp,
                                               const int* __restrict__ src,
                                               const int* __restrict__ dst,
                                               const float* __restrict__ dinv,
                                               int* __restrict__ cursor,
                                               int2* __restrict__ epk,
                                               int E, int gM) {
    constexpr int CT = NC / 16;            // col frags per wave
    constexpr int WJ = NC / 32;            // W gload insts per wave
    constexpr int WBUF = AF32 ? 1 : 2;
    __shared__ __align__(16) _Float16 As[2][64 * 64];
    __shared__ __align__(16) _Float16 Ws[WBUF][NC * 64];
    __shared__ __align__(16) float ssc[128], ssh[128];  // dead-stripped if !BN

    if constexpr (FILL) {
        if ((int)blockIdx.x >= gM) {       // fill path: no barriers used
            int e = (blockIdx.x - gM) * 256 + threadIdx.x;
            if (e < E) {
                int s = src[e], d = dst[e];
                if (s != d) {
                    int pos = atomicAdd(&cursor[d], 1);
                    epk[pos] = make_int2(s, __float_as_int(dinv[s] * dinv[d]));
                }
            }
            return;
        }
    }

    const int tid  = threadIdx.x;
    const int lane = tid & 63, wave = tid >> 6;
    const int lrow = lane & 15, kg = lane >> 4;
    const int row0 = blockIdx.x * 64;

    f32x4 acc[CT] = {};
    float4 aw[4];                          // depth-1 A regs (AF32 path)

    const float*    Af = (const float*)Av;
    const _Float16* Ah = (const _Float16*)Av;

    auto stage = [&](int c0, int b) {
        const int k0 = c0 * 64;
        if constexpr (!AF32) {
            #pragma unroll
            for (int j = 0; j < 2; ++j) {
                int li  = wave * 128 + j * 64 + lane;      // 0..511
                int row = li >> 3, s = li & 7;
                int gr  = row0 + row;
                int gs  = s ^ (row & 7);
                if (gr < M)
                    gload16(Ah + (size_t)gr * Kp + k0 + gs * 8,
                            (char*)&As[b][0] + (wave * 128 + j * 64) * 16);
            }
        }
        #pragma unroll
        for (int j = 0; j < WJ; ++j) {
            int li  = wave * (WJ * 64) + j * 64 + lane;
            int row = li >> 3, s = li & 7;
            int gs  = s ^ (row & 7);
            gload16(Wh + (size_t)row * Kp + k0 + gs * 8,
                    (char*)&Ws[AF32 ? 0 : b][0] + (wave * WJ + j) * 1024);
        }
    };

    // AF32: depth-1 reg-staged A (64 rows x 16 float4 slots, 4 per thread)
    auto load_a = [&](int c0) {
        const int k0 = c0 * 64;
        #pragma unroll
        for (int it = 0; it < 4; ++it) {
            int idx = tid + it * 256;
            int row = idx >> 4, slot = idx & 15;
            int gr = row0 + row, gk = k0 + slot * 4;
            aw[it] = make_float4(0.f, 0.f, 0.f, 0.f);
            if (gr < M && gk < K)                      // K%4==0 -> all-or-none
                aw[it] = *(const float4*)(Af + (size_t)gr * K + gk);
        }
    };
    auto store_a = [&](int b) {
        #pragma unroll
        for (int it = 0; it < 4; ++it) {
            int idx = tid + it * 256;
            int row = idx >> 4, slot = idx & 15;
            f16x4 h;
            h[0] = (_Float16)aw[it].x; h[1] = (_Float16)aw[it].y;
            h[2] = (_Float16)aw[it].z; h[3] = (_Float16)aw[it].w;
            int cb = (slot * 8) ^ ((row & 7) << 4);
            *(f16x4*)((char*)&As[b][0] + row * 128 + cb) = h;
        }
    };

    auto compute = [&](int b, int kofs) {
        const char* AsB = (const char*)&As[b][0];
        const char* WsB = (const char*)&Ws[AF32 ? 0 : b][0];
        #pragma unroll
        for (int ks = 0; ks < 2; ++ks) {
            const int cb = ks * 64 + kg * 16;          // byte offset
            f16x8 af, bf[CT];
            {
                int row = wave * 16 + lrow;
                af = *(const f16x8*)(AsB + row * 128 + (cb ^ ((row & 7) << 4)));
            }
            if constexpr (BN) {
                const int kb = kofs + ks * 32 + kg * 8;
                f32x4 sc0 = *(const f32x4*)&ssc[kb];
                f32x4 sc1 = *(const f32x4*)&ssc[kb + 4];
                f32x4 sh0 = *(const f32x4*)&ssh[kb];
                f32x4 sh1 = *(const f32x4*)&ssh[kb + 4];
                f16x8 a2;
                #pragma unroll
                for (int j = 0; j < 4; ++j) {
                    a2[j]     = (_Float16)fmaxf(0.f, fmaf((float)af[j],     sc0[j], sh0[j]));
                    a2[j + 4] = (_Float16)fmaxf(0.f, fmaf((float)af[j + 4], sc1[j], sh1[j]));
                }
                af = a2;
            }
            #pragma unroll
            for (int ct = 0; ct < CT; ++ct) {
                int row = ct * 16 + lrow;
                bf[ct] = *(const f16x8*)(WsB + row * 128 +
                                         (cb ^ ((row & 7) << 4)));
            }
            #pragma unroll
            for (int ct = 0; ct < CT; ++ct)
                acc[ct] = __builtin_amdgcn_mfma_f32_16x16x32_f16(
                    af, bf[ct], acc[ct], 0, 0, 0);
        }
    };

    if constexpr (BN) {
        if (tid < 128) {                   // Kp == 128 on the BN path
            float mean = gsum[tid] * inv_n;
            float var  = gsq[tid] * inv_n - mean * mean;
            float sc   = rsqrtf(var + EPS_BN);
            ssc[tid] = sc;
            ssh[tid] = -mean * sc;
        }
    }

    const int nchunk = Kp >> 6;            // Kp % 64 == 0

    if constexpr (AF32) {
        // A dbuf (reg-staged), W single-buffer.
        load_a(0);
        store_a(0);
        stage(0, 0);                       // W(0)
        asm volatile("s_waitcnt vmcnt(0) lgkmcnt(0)" ::: "memory");
        __builtin_amdgcn_s_barrier();
        __builtin_amdgcn_sched_barrier(0);
        for (int c = 0; c < nchunk; ++c) {
            const int b = c & 1;
            const bool more = (c + 1 < nchunk);
            if (more) load_a(c + 1);       // A loads fly during compute
            compute(b, 0);
            if (more) {
                store_a(b ^ 1);            // conv + ds_write (waits A loads)
                __builtin_amdgcn_s_barrier();   // all waves done reading W(c)
                __builtin_amdgcn_sched_barrier(0);
                stage(c + 1, 0);           // W(c+1) into the single buffer
                asm volatile("s_waitcnt vmcnt(0) lgkmcnt(0)" ::: "memory");
                __builtin_amdgcn_s_barrier();
                __builtin_amdgcn_sched_barrier(0);
            }
        }
    } else {
        stage(0, 0);
        asm volatile("s_waitcnt vmcnt(0) lgkmcnt(0)" ::: "memory");
        __builtin_amdgcn_s_barrier();
        __builtin_amdgcn_sched_barrier(0);
        for (int c = 0; c < nchunk; ++c) {
            const int b = c & 1;
            const bool more = (c + 1 < nchunk);
            if (more) stage(c + 1, b ^ 1);
            compute(b, c * 64);
            if (more) {
                asm volatile("s_waitcnt vmcnt(0) lgkmcnt(0)" ::: "memory");
                __builtin_amdgcn_s_barrier();
                __builtin_amdgcn_sched_barrier(0);
            }
        }
    }

    // ---- epilogue: D lane map col=lane&15, row=(lane>>4)*4+r ----
    #pragma unroll
    for (int r = 0; r < 4; ++r) {
        int grow = row0 + wave * 16 + kg * 4 + r;
        if (grow >= M) continue;
        #pragma unroll
        for (int ct = 0; ct < CT; ++ct)
            C[(size_t)grow * NC + ct * 16 + lrow] = (_Float16)acc[ct][r];
    }
}

// ---------------- GCN aggregation (gather over CSR, f16 in/out) ----------------
// 4 nodes/wave (16 lanes x f16x8), software-pipelined edge records (R14).

__global__ void agg128_k(const _Float16* __restrict__ h, const float* __restrict__ invdeg,
                         const int* __restrict__ row_start, const int* __restrict__ cnt,
                         const int2* __restrict__ epk,
                         const float* __restrict__ bias, _Float16* __restrict__ out, int n) {
    const int grp = threadIdx.x >> 4;           // 0..15 node-groups per block
    const int l = threadIdx.x & 15;
    const int i = blockIdx.x * 16 + grp;
    if (i >= n) return;
    const int st = row_start[i], en = st + cnt[i];
    const float id = invdeg[i];
    const int c = l * 8;

    float a[8];
    {
        f16x8 hv = *(const f16x8*)(h + (size_t)i * 128 + c);
        #pragma unroll
        for (int j = 0; j < 8; ++j)
            a[j] = fmaf(id, (float)hv[j], bias[c + j]);
    }

    auto gfma = [&](int2 e0, int2 e1, int2 e2, int2 e3) {
        f16x8 v0 = *(const f16x8*)(h + (size_t)e0.x * 128 + c);
        f16x8 v1 = *(const f16x8*)(h + (size_t)e1.x * 128 + c);
        f16x8 v2 = *(const f16x8*)(h + (size_t)e2.x * 128 + c);
        f16x8 v3 = *(const f16x8*)(h + (size_t)e3.x * 128 + c);
        float w0 = __int_as_float(e0.y), w1 = __int_as_float(e1.y);
        float w2 = __int_as_float(e2.y), w3 = __int_as_float(e3.y);
        #pragma unroll
        for (int j = 0; j < 8; ++j) {
            a[j] = fmaf(w0, (float)v0[j], a[j]);
            a[j] = fmaf(w1, (float)v1[j], a[j]);
            a[j] = fmaf(w2, (float)v2[j], a[j]);
            a[j] = fmaf(w3, (float)v3[j], a[j]);
        }
    };

    int p = st;
    if (p + 3 < en) {
        int2 eA0 = epk[p], eA1 = epk[p + 1], eA2 = epk[p + 2], eA3 = epk[p + 3];
        while (p + 7 < en) {
            int2 eB0 = epk[p + 4], eB1 = epk[p + 5];
            int2 eB2 = epk[p + 6], eB3 = epk[p + 7];
            gfma(eA0, eA1, eA2, eA3);
            eA0 = eB0; eA1 = eB1; eA2 = eB2; eA3 = eB3;
            p += 4;
        }
        gfma(eA0, eA1, eA2, eA3);
        p += 4;
    }
    for (; p < en; ++p) {
        int2 e0 = epk[p];
        float w0 = __int_as_float(e0.y);
        f16x8 v0 = *(const f16x8*)(h + (size_t)e0.x * 128 + c);
        #pragma unroll
        for (int j = 0; j < 8; ++j)
            a[j] = fmaf(w0, (float)v0[j], a[j]);
    }
    f16x8 o;
    #pragma unroll
    for (int j = 0; j < 8; ++j) o[j] = (_Float16)a[j];
    *(f16x8*)(out + (size_t)i * 128 + c) = o;
}

// ---------------- BN stats over f16 activations (12.8 MB read) ----------------

__global__ void stats16_k(const _Float16* __restrict__ a, float* __restrict__ gsum,
                          float* __restrict__ gsq, int total8) {
    const int tid = threadIdx.x;
    float s[8] = {}, q[8] = {};
    for (int idx = blockIdx.x * 256 + tid; idx < total8; idx += gridDim.x * 256) {
        f16x8 v = *(const f16x8*)(a + (size_t)idx * 8);
        #pragma unroll
        for (int j = 0; j < 8; ++j) {
            float f = (float)v[j];
            s[j] += f;
            q[j] = fmaf(f, f, q[j]);
        }
    }
    __shared__ float red[2][16][16][8];     // [sum/sq][k-group][col-group][col]
    const int g = tid & 15, k = tid >> 4;
    #pragma unroll
    for (int j = 0; j < 8; ++j) {
        red[0][k][g][j] = s[j];
        red[1][k][g][j] = q[j];
    }
    __syncthreads();
    if (tid < 128) {
        const int g2 = tid & 15, j2 = tid >> 4;     // j2 in 0..7
        float ts = 0.f, tq = 0.f;
        #pragma unroll
        for (int k2 = 0; k2 < 16; ++k2) {
            ts += red[0][k2][g2][j2];
            tq += red[1][k2][g2][j2];
        }
        atomicAdd(&gsum[g2 * 8 + j2], ts);
        atomicAdd(&gsq[g2 * 8 + j2], tq);
    }
}

// ---- classifier agg (64 cols) + log_softmax; 8 nodes/wave, pipelined ----
// 8 lanes per node, f16x8 per lane (full row); shfl_xor d<=4 stays in-group.

__global__ void aggsm_k(const _Float16* __restrict__ h, const float* __restrict__ invdeg,
                        const int* __restrict__ row_start, const int* __restrict__ cnt,
                        const int2* __restrict__ epk,
                        const float* __restrict__ bias, float* __restrict__ out, int n) {
    const int grp = threadIdx.x >> 3;           // 0..31 node-groups per block
    const int l = threadIdx.x & 7;
    const int i = blockIdx.x * 32 + grp;
    if (i >= n) return;
    const int st = row_start[i], en = st + cnt[i];
    const float id = invdeg[i];
    const int c = l * 8;

    float a[8];
    {
        f16x8 hv = *(const f16x8*)(h + (size_t)i * 64 + c);
        #pragma unroll
        for (int j = 0; j < 8; ++j)
            a[j] = fmaf(id, (float)hv[j], bias[c + j]);
    }

    auto gfma = [&](int2 e0, int2 e1, int2 e2, int2 e3) {
        f16x8 v0 = *(const f16x8*)(h + (size_t)e0.x * 64 + c);
        f16x8 v1 = *(const f16x8*)(h + (size_t)e1.x * 64 + c);
        f16x8 v2 = *(const f16x8*)(h + (size_t)e2.x * 64 + c);
        f16x8 v3 = *(const f16x8*)(h + (size_t)e3.x * 64 + c);
        float w0 = __int_as_float(e0.y), w1 = __int_as_float(e1.y);
        float w2 = __int_as_float(e2.y), w3 = __int_as_float(e3.y);
        #pragma unroll
        for (int j = 0; j < 8; ++j) {
            a[j] = fmaf(w0, (float)v0[j], a[j]);
            a[j] = fmaf(w1, (float)v1[j], a[j]);
            a[j] = fmaf(w2, (float)v2[j], a[j]);
            a[j] = fmaf(w3, (float)v3[j], a[j]);
        }
    };

    int p = st;
    if (p + 3 < en) {
        int2 eA0 = epk[p], eA1 = epk[p + 1], eA2 = epk[p + 2], eA3 = epk[p + 3];
        while (p + 7 < en) {
            int2 eB0 = epk[p + 4], eB1 = epk[p + 5];
            int2 eB2 = epk[p + 6], eB3 = epk[p + 7];
            gfma(eA0, eA1, eA2, eA3);
            eA0 = eB0; eA1 = eB1; eA2 = eB2; eA3 = eB3;
            p += 4;
        }
        gfma(eA0, eA1, eA2, eA3);
        p += 4;
    }
    for (; p < en; ++p) {
        int2 e0 = epk[p];
        float w0 = __int_as_float(e0.y);
        f16x8 v0 = *(const f16x8*)(h + (size_t)e0.x * 64 + c);
        #pragma unroll
        for (int j = 0; j < 8; ++j)
            a[j] = fmaf(w0, (float)v0[j], a[j]);
    }

    // fused log_softmax over 64 cols held by this 8-lane group
    float m = a[0];
    #pragma unroll
    for (int j = 1; j < 8; ++j) m = fmaxf(m, a[j]);
    #pragma unroll
    for (int d = 4; d >= 1; d >>= 1) m = fmaxf(m, __shfl_xor(m, d, 64));
    float s = 0.f;
    float e[8];
    #pragma unroll
    for (int j = 0; j < 8; ++j) { e[j] = __expf(a[j] - m); s += e[j]; }
    #pragma unroll
    for (int d = 4; d >= 1; d >>= 1) s += __shfl_xor(s, d, 64);
    float ls = __logf(s);
    float4 o0 = make_float4(a[0] - m - ls, a[1] - m - ls,
                            a[2] - m - ls, a[3] - m - ls);
    float4 o1 = make_float4(a[4] - m - ls, a[5] - m - ls,
                            a[6] - m - ls, a[7] - m - ls);
    *(float4*)(out + (size_t)i * 64 + c)     = o0;
    *(float4*)(out + (size_t)i * 64 + c + 4) = o1;
}

// ---------------------------------------------------------------------------

extern "C" void kernel_launch(void* const* d_in, const int* in_sizes, int n_in,
                              void* d_out, int out_size, void* d_ws, size_t ws_size,
                              hipStream_t stream) {
    const float* x  = (const float*)d_in[0];
    const int*   ei = (const int*)d_in[1];
    const float* W0 = (const float*)d_in[2];
    const float* b0 = (const float*)d_in[3];
    const float* W1 = (const float*)d_in[4];
    const float* b1 = (const float*)d_in[5];
    const float* W2 = (const float*)d_in[6];
    const float* b2 = (const float*)d_in[7];

    const int IN = 500;
    const int n = in_sizes[0] / IN;      // 50000
    const int E = in_sizes[1] / 2;       // 640000
    const int* src = ei;
    const int* dst = ei + E;

    // ---- workspace bump allocator (256B aligned) ----
    char* p = (char*)d_ws;
    auto alloc = [&](size_t bytes) -> void* {
        char* r = p;
        p += (bytes + 255) & ~(size_t)255;
        return (void*)r;
    };
    _Float16*  hb1h    = (_Float16*)alloc((size_t)n * 128 * 2);  // GEMM out / agg in
    _Float16*  hb2a    = (_Float16*)alloc((size_t)n * 128 * 2);  // agg out (pre-BN f16)
    _Float16*  W0h     = (_Float16*)alloc((size_t)128 * 512 * 2);
    _Float16*  W1h     = (_Float16*)alloc((size_t)128 * 128 * 2);
    _Float16*  W2h     = (_Float16*)alloc((size_t)64 * 128 * 2);
    // deg_cnt + BN stat buffers allocated contiguously -> single memset
    int*   deg_cnt  = (int*)alloc((size_t)n * 4);
    float* gsum0    = (float*)alloc(128 * 4);
    float* gsq0     = (float*)alloc(128 * 4);
    float* gsum1    = (float*)alloc(128 * 4);
    float* gsq1     = (float*)alloc(128 * 4);
    char*  zero_end = p;
    float* dinv     = (float*)alloc((size_t)n * 4);
    float* invdeg   = (float*)alloc((size_t)n * 4);
    int*   row_st   = (int*)alloc((size_t)n * 4);
    int*   cursor   = (int*)alloc((size_t)n * 4);
    int*   within   = (int*)alloc((size_t)n * 4);
    int*   btot     = (int*)alloc(256 * 4);
    int2*  epk      = (int2*)alloc((size_t)E * 8);
    (void)ws_size; (void)n_in; (void)out_size;

    float* out = (float*)d_out;
    const float inv_n = 1.0f / (float)n;

    const int gE = (E + 255) / 256;      // 2500
    const int gN = (n + 255) / 256;
    const int nblk = (n + 511) / 512;
    const int gM = (n + 63) / 64;        // 782 blocks
    const int gA = (n + 15) / 16;        // 3125 blocks (agg128)
    const int gS = (n + 31) / 32;        // 1563 blocks (aggsm, 8 nodes/wave)

    // ---- graph prep + weight conversion (once per call) ----
    hipMemsetAsync(deg_cnt, 0, (size_t)(zero_end - (char*)deg_cnt), stream);
    countw_k<<<gE + 88, 256, 0, stream>>>(src, dst, deg_cnt, E, gE,
                                          W0, W0h, W1, W1h, W2, W2h);
    scan1_k<<<nblk, 512, 0, stream>>>(deg_cnt, within, btot, n);
    scan3_k<<<gN, 256, 0, stream>>>(within, btot, deg_cnt, row_st, cursor,
                                    dinv, invdeg, n);

    // ---- layer 0: GEMM0 + CSR fill in ONE launch (independent work) ----
    mgemm_k<128, false, true, true><<<gM + gE, 256, 0, stream>>>(
        x, W0h, hb1h, nullptr, nullptr, 0.f, n, 500, 512,
        src, dst, dinv, cursor, epk, E, gM);
    agg128_k<<<gA, 256, 0, stream>>>(hb1h, invdeg, row_st, deg_cnt, epk, b0, hb2a, n);
    stats16_k<<<256, 256, 0, stream>>>(hb2a, gsum0, gsq0, n * 16);

    // ---- layer 1 (BN0+ReLU fused into GEMM1's A path) ----
    mgemm_k<128, true, false, false><<<gM, 256, 0, stream>>>(
        hb2a, W1h, hb1h, gsum0, gsq0, inv_n, n, 128, 128,
        nullptr, nullptr, nullptr, nullptr, nullptr, 0, gM);
    agg128_k<<<gA, 256, 0, stream>>>(hb1h, invdeg, row_st, deg_cnt, epk, b1, hb2a, n);
    stats16_k<<<256, 256, 0, stream>>>(hb2a, gsum1, gsq1, n * 16);

    // ---- classifier (BN1+ReLU fused into GEMM2; log_softmax fused into agg) ----
    mgemm_k<64, true, false, false><<<gM, 256, 0, stream>>>(
        hb2a, W2h, hb1h, gsum1, gsq1, inv_n, n, 128, 128,
        nullptr, nullptr, nullptr, nullptr, nullptr, 0, gM);
    aggsm_k<<<gS, 256, 0, stream>>>(hb1h, invdeg, row_st, deg_cnt, epk, b2, out, n);
}